// Round 5
// baseline (220.810 us; speedup 1.0000x reference)
//
#include <hip/hip_runtime.h>

// confidence_maps: (8,6,4,512,512) f32; warp_masks: (8,1,512,512) f32;
// gauss_kernel: (1,1,5,5) f32.
// Output: mask (48,1,512,512) f32 + rate scalar = 12,582,913 floats.
//
// Validated invariants (rounds 1-4, absmax 0.0):
//  - rate == 0.5 exactly; ego rows (l==0) all-ones, excluded from rate.
//  - max_c(sigmoid) == sigmoid(max_c).
//  - f64 finalize formula (m_val + fixed fma chain) matches np ref ordering.
//
// Round-5 change (round-4 post-mortem: compute ~100us dominated by f64 exp +
// f64 FMA + 8B LDS tile): hot path is now all-f32. u16 key = floor(v32*2^16).
// |v32 - v64| <= ~2e-6 << bin width 1.53e-5, so a +/-2-bin band around the
// 16-bit cutoff provably contains every element whose in/out status differs
// between f32 and f64. Only those ~300-600/row get the exact f64 recompute +
// exact (value desc, index asc) rank in finalize. Selection counts (A2) are
// exact integer counts of the stored keys, so R = K - A2 + #(cand keys>pstar).

#define NROWSEL 40
#define NPIX    262144
#define KSEL    131072
#define CAND_CAP 4096
#define KAPPA    2            // band half-width in 16-bit bins

// ---- workspace layout (bytes) ----
#define OFF_KEY  0ull                  // 40*262144 u16 = 20,971,520
#define OFF_H1   20971520ull           // 40*256 u32    =     40,960
#define OFF_H2   21012480ull           // 40*256 u32    =     40,960
#define OFF_ST   21053440ull           // 40*4 int      =        640
#define OFF_CC   21054080ull           // 40 u32        =        160
#define OFF_CI   21054240ull           // 40*4096 int   =    655,360
#define OFF_CK   21709600ull           // 40*4096 u16   =    327,680
#define META_BYTES 82720ull            // zero H1 + H2 + ST + CC

// fast f32 m = sigmoid(max_c conf) * warp  (hot path, approximate)
__device__ __forceinline__ float m_val_f32(const float* __restrict__ confr,
                                           const float* __restrict__ warpr,
                                           int gy, int gx) {
  if (gy < 0 || gy >= 512 || gx < 0 || gx >= 512) return 0.0f;
  int off = gy * 512 + gx;
  float x0 = confr[off];
  float x1 = confr[NPIX + off];
  float x2 = confr[2 * NPIX + off];
  float x3 = confr[3 * NPIX + off];
  float mx = fmaxf(fmaxf(x0, x1), fmaxf(x2, x3));
  float s = 1.0f / (1.0f + expf(-mx));
  return s * warpr[off];
}

// exact f64 m — IDENTICAL to rounds 1-4 (absmax 0.0); used only in finalize.
__device__ __forceinline__ double m_val(const float* __restrict__ confr,
                                        const float* __restrict__ warpr,
                                        int gy, int gx) {
  if (gy < 0 || gy >= 512 || gx < 0 || gx >= 512) return 0.0;
  int off = gy * 512 + gx;
  float x0 = confr[off];
  float x1 = confr[NPIX + off];
  float x2 = confr[2 * NPIX + off];
  float x3 = confr[3 * NPIX + off];
  float mx = fmaxf(fmaxf(x0, x1), fmaxf(x2, x3));
  double s = 1.0 / (1.0 + exp(-(double)mx));
  return s * (double)warpr[off];
}

__global__ void ego_fill_kernel(float* __restrict__ out) {
  int i = blockIdx.x * 256 + threadIdx.x;   // 524288 float4 units
  int b = i >> 16;
  int o4 = i & 65535;
  float4* p = (float4*)(out + (size_t)b * 6u * NPIX) + o4;
  *p = make_float4(1.f, 1.f, 1.f, 1.f);
}

// Fused f32: m halo tile (68x68) in LDS, 25-tap f32 conv, u16 key store,
// 256-bin LDS histogram of key high byte.
__global__ __launch_bounds__(256) void compute_kernel(
    const float* __restrict__ conf, const float* __restrict__ warp,
    const float* __restrict__ gk, unsigned short* __restrict__ keys,
    unsigned* __restrict__ hist1) {
  const int blk = blockIdx.x;        // 40 * 64
  const int j = blk >> 6;            // row 0..39
  const int tile = blk & 63;         // 8x8 tiles of 64x64
  const int ty0 = (tile >> 3) << 6;
  const int tx0 = (tile & 7) << 6;
  const int b = j / 5;
  const int l = j % 5 + 1;
  const int rowg = b * 6 + l;
  const float* confr = conf + (size_t)rowg * 4u * NPIX;
  const float* warpr = warp + (size_t)b * NPIX;

  __shared__ float mt[68][68];       // 18496 B
  __shared__ float g[25];
  __shared__ unsigned lh[256];       // 1024 B => ~19.7 KB total
  const int tid = threadIdx.x;
  if (tid < 25) g[tid] = gk[tid];
  lh[tid] = 0u;

  for (int i = tid; i < 68 * 68; i += 256) {
    int hy = i / 68, hx = i % 68;
    mt[hy][hx] = m_val_f32(confr, warpr, ty0 + hy - 2, tx0 + hx - 2);
  }
  __syncthreads();

  const int txl = tid & 63;
  const int tyl = tid >> 6;          // 0..3
  unsigned short* keyrow = keys + (size_t)j * NPIX;
  for (int rr = 0; rr < 16; ++rr) {
    int yy = tyl + (rr << 2);        // 0..63
    float acc = 0.0f;
#pragma unroll
    for (int dy = 0; dy < 5; ++dy)
#pragma unroll
      for (int dx = 0; dx < 5; ++dx)
        acc = fmaf(g[dy * 5 + dx], mt[yy + dy][txl + dx], acc);
    unsigned k = (unsigned)fminf(fmaxf(acc * 65536.0f, 0.0f), 65535.0f);
    keyrow[(ty0 + yy) * 512 + (tx0 + txl)] = (unsigned short)k;
    atomicAdd(&lh[k >> 8], 1u);
  }
  __syncthreads();
  if (lh[tid]) atomicAdd(&hist1[j * 256 + tid], lh[tid]);
}

// Coarse: find high-byte bin b1 (descending); A1 = count strictly above.
__global__ void scan1_kernel(const unsigned* __restrict__ hist1,
                             int* __restrict__ st) {
  int j = blockIdx.x;
  const unsigned* h = hist1 + j * 256;
  __shared__ unsigned cs[256];
  int tid = threadIdx.x;
  cs[tid] = h[tid];
  __syncthreads();
  if (tid == 0) {
    unsigned cum = 0; int b1 = 255; unsigned A1 = 0;
    for (int c = 255; c >= 0; --c) {
      if (cum + cs[c] >= (unsigned)KSEL) { b1 = c; A1 = cum; break; }
      cum += cs[c];
    }
    st[j * 4 + 0] = b1;
    st[j * 4 + 1] = (int)A1;
  }
}

// Refine: histogram low byte for u16 keys whose high byte == b1.
__global__ __launch_bounds__(256) void hist2_kernel(
    const unsigned short* __restrict__ keys, const int* __restrict__ st,
    unsigned* __restrict__ hist2) {
  int blk = blockIdx.x;              // 40 * 32
  int j = blk >> 5, seg = blk & 31;  // 8192 keys per segment
  unsigned b1 = (unsigned)st[j * 4 + 0];
  const uint4* kp = (const uint4*)(keys + (size_t)j * NPIX + seg * 8192);
  __shared__ unsigned lh[256];
  lh[threadIdx.x] = 0u;
  __syncthreads();
#pragma unroll
  for (int it = 0; it < 4; ++it) {
    uint4 k4 = kp[threadIdx.x + it * 256];
    unsigned w[4] = {k4.x, k4.y, k4.z, k4.w};
#pragma unroll
    for (int e = 0; e < 4; ++e) {
      unsigned lo = w[e] & 0xFFFFu, hi = w[e] >> 16;
      if ((lo >> 8) == b1) atomicAdd(&lh[lo & 255u], 1u);
      if ((hi >> 8) == b1) atomicAdd(&lh[hi & 255u], 1u);
    }
  }
  __syncthreads();
  if (lh[threadIdx.x]) atomicAdd(&hist2[j * 256 + threadIdx.x], lh[threadIdx.x]);
}

// pstar = (b1<<8)|b2 (full u16 prefix); A2 = exact count of keys > pstar.
__global__ void scan2_kernel(const unsigned* __restrict__ hist2,
                             int* __restrict__ st) {
  int j = blockIdx.x;
  const unsigned* h = hist2 + j * 256;
  __shared__ unsigned cs[256];
  int tid = threadIdx.x;
  cs[tid] = h[tid];
  __syncthreads();
  if (tid == 0) {
    unsigned b1 = (unsigned)st[j * 4 + 0];
    unsigned A1 = (unsigned)st[j * 4 + 1];
    unsigned cum = A1; int b2 = 255; unsigned A2 = A1;
    for (int c = 255; c >= 0; --c) {
      if (cum + cs[c] >= (unsigned)KSEL) { b2 = c; A2 = cum; break; }
      cum += cs[c];
    }
    st[j * 4 + 2] = (int)((b1 << 8) | (unsigned)b2);
    st[j * 4 + 3] = (int)A2;
  }
}

// Decided bits: key > pstar+KAPPA -> 1, key < pstar-KAPPA -> 0.
// In-band keys -> gather (idx, key) for exact f64 resolution.
__global__ __launch_bounds__(256) void mask_gather_kernel(
    const unsigned short* __restrict__ keys, const int* __restrict__ st,
    float* __restrict__ out, unsigned* __restrict__ ccount,
    int* __restrict__ cidx, unsigned short* __restrict__ ckey) {
  int blk = blockIdx.x;              // 40 * 32
  int j = blk >> 5, seg = blk & 31;
  int b = j / 5, l = j % 5 + 1;
  int rowg = b * 6 + l;
  int pstar = st[j * 4 + 2];
  const uint4* kp = (const uint4*)(keys + (size_t)j * NPIX + seg * 8192);
  float4* o4 = (float4*)(out + (size_t)rowg * NPIX + seg * 8192);
#pragma unroll
  for (int it = 0; it < 4; ++it) {
    int q = threadIdx.x + it * 256;
    uint4 k4 = kp[q];                // 8 u16 keys
    unsigned w[4] = {k4.x, k4.y, k4.z, k4.w};
    float4 mv[2];
    float* mf = (float*)mv;
#pragma unroll
    for (int e = 0; e < 4; ++e) {
      int lo = (int)(w[e] & 0xFFFFu);
      int hi = (int)(w[e] >> 16);
      mf[e * 2]     = lo > pstar + KAPPA ? 1.f : 0.f;
      mf[e * 2 + 1] = hi > pstar + KAPPA ? 1.f : 0.f;
      if (lo >= pstar - KAPPA && lo <= pstar + KAPPA) {
        unsigned s = atomicAdd(&ccount[j], 1u);
        if (s < CAND_CAP) { cidx[j * CAND_CAP + s] = seg * 8192 + q * 8 + e * 2;
                            ckey[j * CAND_CAP + s] = (unsigned short)lo; }
      }
      if (hi >= pstar - KAPPA && hi <= pstar + KAPPA) {
        unsigned s = atomicAdd(&ccount[j], 1u);
        if (s < CAND_CAP) { cidx[j * CAND_CAP + s] = seg * 8192 + q * 8 + e * 2 + 1;
                            ckey[j * CAND_CAP + s] = (unsigned short)hi; }
      }
    }
    o4[q * 2] = mv[0];
    o4[q * 2 + 1] = mv[1];
  }
}

// Exact f64 recompute of band candidates (identical formula to rounds 1-4),
// exact rank with (value desc, index asc) tie-break.
// R = K - A2 + #(cand key > pstar)  ==  K - #(key > pstar+KAPPA).
__global__ __launch_bounds__(256) void finalize_kernel(
    const float* __restrict__ conf, const float* __restrict__ warp,
    const float* __restrict__ gk, const int* __restrict__ st,
    const unsigned* __restrict__ ccount, const int* __restrict__ cidx,
    const unsigned short* __restrict__ ckey, float* __restrict__ out) {
  int j = blockIdx.x;
  int b = j / 5, l = j % 5 + 1;
  int rowg = b * 6 + l;
  const float* confr = conf + (size_t)rowg * 4u * NPIX;
  const float* warpr = warp + (size_t)b * NPIX;
  __shared__ double vs[CAND_CAP];    // 32 KB
  __shared__ int ids[CAND_CAP];      // 16 KB
  __shared__ double g[25];
  int tid = threadIdx.x;
  if (tid < 25) g[tid] = (double)gk[tid];
  int pstar = st[j * 4 + 2];
  int A2 = st[j * 4 + 3];
  int C = (int)min(ccount[j], (unsigned)CAND_CAP);
  __syncthreads();
  for (int i = tid; i < C; i += 256) {
    int idx = cidx[j * CAND_CAP + i];
    int y = idx >> 9, x = idx & 511;
    double acc = 0.0;
#pragma unroll
    for (int dy = 0; dy < 5; ++dy)
#pragma unroll
      for (int dx = 0; dx < 5; ++dx)
        acc = fma(g[dy * 5 + dx], m_val(confr, warpr, y + dy - 2, x + dx - 2), acc);
    vs[i] = acc;
    ids[i] = idx;
  }
  __syncthreads();
  int cntAbove = 0;
  for (int q = 0; q < C; ++q)
    cntAbove += (int)ckey[j * CAND_CAP + q] > pstar ? 1 : 0;
  int R = KSEL - A2 + cntAbove;
  for (int i = tid; i < C; i += 256) {
    double vi = vs[i];
    int ii = ids[i];
    int rank = 0;
    for (int q = 0; q < C; ++q) {
      double vq = vs[q];
      rank += (vq > vi) || (vq == vi && ids[q] < ii) ? 1 : 0;
    }
    if (rank < R) out[(size_t)rowg * NPIX + ii] = 1.0f;
  }
  if (j == 0 && tid == 0) out[12582912] = 0.5f;  // rate == 0.5 exactly
}

extern "C" void kernel_launch(void* const* d_in, const int* in_sizes, int n_in,
                              void* d_out, int out_size, void* d_ws, size_t ws_size,
                              hipStream_t stream) {
  const float* conf = (const float*)d_in[0];
  const float* warp = (const float*)d_in[1];
  const float* gk   = (const float*)d_in[2];
  float* out = (float*)d_out;
  char* ws = (char*)d_ws;

  unsigned short* keys = (unsigned short*)(ws + OFF_KEY);
  unsigned* h1 = (unsigned*)(ws + OFF_H1);
  unsigned* h2 = (unsigned*)(ws + OFF_H2);
  int*      st = (int*)(ws + OFF_ST);
  unsigned* cc = (unsigned*)(ws + OFF_CC);
  int*      ci = (int*)(ws + OFF_CI);
  unsigned short* ck = (unsigned short*)(ws + OFF_CK);

  hipMemsetAsync(ws + OFF_H1, 0, (size_t)META_BYTES, stream);

  ego_fill_kernel<<<2048, 256, 0, stream>>>(out);
  compute_kernel<<<NROWSEL * 64, 256, 0, stream>>>(conf, warp, gk, keys, h1);
  scan1_kernel<<<NROWSEL, 256, 0, stream>>>(h1, st);
  hist2_kernel<<<NROWSEL * 32, 256, 0, stream>>>(keys, st, h2);
  scan2_kernel<<<NROWSEL, 256, 0, stream>>>(h2, st);
  mask_gather_kernel<<<NROWSEL * 32, 256, 0, stream>>>(keys, st, out, cc, ci, ck);
  finalize_kernel<<<NROWSEL, 256, 0, stream>>>(conf, warp, gk, st, cc, ci, ck, out);
}

// Round 6
// 207.337 us; speedup vs baseline: 1.0650x; 1.0650x over previous
//
#include <hip/hip_runtime.h>

// confidence_maps: (8,6,4,512,512) f32; warp_masks: (8,1,512,512) f32;
// gauss_kernel: (1,1,5,5) f32.
// Output: mask (48,1,512,512) f32 + rate scalar = 12,582,913 floats.
//
// Validated invariants (rounds 1-5, absmax 0.0):
//  - rate == 0.5 exactly; ego rows (l==0) all-ones, excluded from rate.
//  - max_c(sigmoid) == sigmoid(max_c).
//  - selection = exact integer counts of stored u16 keys (pstar, A2), f32 key
//    error band +/-KAPPA bins, exact f64 resolve of band candidates.
//    Proof needs (KAPPA-1)*q > 2*eps and 2*eps <= q; eps(f32 path) ~ 1e-6,
//    q = 2^-16 = 1.53e-5 -> KAPPA=2 valid with >7x margin.
//  - f64 ranking needs only ACCURACY (inter-value spacing ~4e-7 >> 1e-16),
//    not bit-identity -> recompute order/parallelism is free.
//
// Round-6 changes (round-5 post-mortem: finalize at 40 blocks / 1.6% occ with
// ~250 cands x 125 scattered loads regressed to ~130us — round-3 pathology):
//  - finalize split: cand_eval (640 blocks, 1 thread/candidate, strided) +
//    rank_write (40 blocks, LDS rank only).
//  - separable gaussian (factors from gk middle row/col, ~2ulp): 25 -> 10 taps.
//  - coarse histogram moved out of compute into a streaming hist1 pass with
//    8-copy privatized LDS bins (hot-bin contention /8); compute is atomic-free.

#define NROWSEL 40
#define NPIX    262144
#define KSEL    131072
#define CAND_CAP 4096
#define KAPPA    2

// ---- workspace layout (bytes) ----
#define OFF_KEY  0ull                  // 40*262144 u16 = 20,971,520
#define OFF_H1   20971520ull           // 40*256 u32    =     40,960
#define OFF_H2   21012480ull           // 40*256 u32    =     40,960
#define OFF_ST   21053440ull           // 40*4 int      =        640
#define OFF_CC   21054080ull           // 40 u32        =        160
#define OFF_CI   21054240ull           // 40*4096 int   =    655,360
#define OFF_CK   21709600ull           // 40*4096 u16   =    327,680
#define OFF_CV   22037280ull           // 40*4096 f64   =  1,310,720
#define META_BYTES 82720ull            // zero H1 + H2 + ST + CC

// fast f32 m = sigmoid(max_c conf) * warp  (hot path, approximate)
__device__ __forceinline__ float m_val_f32(const float* __restrict__ confr,
                                           const float* __restrict__ warpr,
                                           int gy, int gx) {
  if (gy < 0 || gy >= 512 || gx < 0 || gx >= 512) return 0.0f;
  int off = gy * 512 + gx;
  float x0 = confr[off];
  float x1 = confr[NPIX + off];
  float x2 = confr[2 * NPIX + off];
  float x3 = confr[3 * NPIX + off];
  float mx = fmaxf(fmaxf(x0, x1), fmaxf(x2, x3));
  float s = 1.0f / (1.0f + expf(-mx));
  return s * warpr[off];
}

// exact f64 m — identical formula to rounds 1-5; used only in cand_eval.
__device__ __forceinline__ double m_val(const float* __restrict__ confr,
                                        const float* __restrict__ warpr,
                                        int gy, int gx) {
  if (gy < 0 || gy >= 512 || gx < 0 || gx >= 512) return 0.0;
  int off = gy * 512 + gx;
  float x0 = confr[off];
  float x1 = confr[NPIX + off];
  float x2 = confr[2 * NPIX + off];
  float x3 = confr[3 * NPIX + off];
  float mx = fmaxf(fmaxf(x0, x1), fmaxf(x2, x3));
  double s = 1.0 / (1.0 + exp(-(double)mx));
  return s * (double)warpr[off];
}

__global__ void ego_fill_kernel(float* __restrict__ out) {
  int i = blockIdx.x * 256 + threadIdx.x;   // 524288 float4 units
  int b = i >> 16;
  int o4 = i & 65535;
  float4* p = (float4*)(out + (size_t)b * 6u * NPIX) + o4;
  *p = make_float4(1.f, 1.f, 1.f, 1.f);
}

// Separable f32 conv: m halo (68x68) -> horizontal (68x64) -> vertical + u16
// key store. No histogram, no atomics. LDS ~36 KB -> 4 blocks/CU.
__global__ __launch_bounds__(256) void compute_kernel(
    const float* __restrict__ conf, const float* __restrict__ warp,
    const float* __restrict__ gk, unsigned short* __restrict__ keys) {
  const int blk = blockIdx.x;        // 40 * 64
  const int j = blk >> 6;            // row 0..39
  const int tile = blk & 63;         // 8x8 tiles of 64x64
  const int ty0 = (tile >> 3) << 6;
  const int tx0 = (tile & 7) << 6;
  const int b = j / 5;
  const int l = j % 5 + 1;
  const int rowg = b * 6 + l;
  const float* confr = conf + (size_t)rowg * 4u * NPIX;
  const float* warpr = warp + (size_t)b * NPIX;

  __shared__ float mt[68][68];       // 18496 B
  __shared__ float ht[68][64];       // 17408 B
  __shared__ float wr[5], wc[5];
  const int tid = threadIdx.x;
  if (tid < 5) {
    wr[tid] = gk[10 + tid];               // c * a_dx  (middle row)
    wc[tid] = gk[tid * 5 + 2] / gk[12];   // a_dy      (middle col / center)
  }

  for (int i = tid; i < 68 * 68; i += 256) {
    int hy = i / 68, hx = i - hy * 68;
    mt[hy][hx] = m_val_f32(confr, warpr, ty0 + hy - 2, tx0 + hx - 2);
  }
  __syncthreads();

  for (int i = tid; i < 68 * 64; i += 256) {
    int hy = i >> 6, x = i & 63;
    float a = mt[hy][x] * wr[0];
    a = fmaf(wr[1], mt[hy][x + 1], a);
    a = fmaf(wr[2], mt[hy][x + 2], a);
    a = fmaf(wr[3], mt[hy][x + 3], a);
    a = fmaf(wr[4], mt[hy][x + 4], a);
    ht[hy][x] = a;
  }
  __syncthreads();

  const int txl = tid & 63;
  const int tyl = tid >> 6;          // 0..3
  unsigned short* keyrow = keys + (size_t)j * NPIX;
  for (int rr = 0; rr < 16; ++rr) {
    int yy = tyl + (rr << 2);        // 0..63
    float acc = ht[yy][txl] * wc[0];
    acc = fmaf(wc[1], ht[yy + 1][txl], acc);
    acc = fmaf(wc[2], ht[yy + 2][txl], acc);
    acc = fmaf(wc[3], ht[yy + 3][txl], acc);
    acc = fmaf(wc[4], ht[yy + 4][txl], acc);
    unsigned k = (unsigned)fminf(fmaxf(acc * 65536.0f, 0.0f), 65535.0f);
    keyrow[(ty0 + yy) * 512 + (tx0 + txl)] = (unsigned short)k;
  }
}

// Streaming coarse histogram (key high byte), 8-copy privatized LDS bins.
__global__ __launch_bounds__(256) void hist1_kernel(
    const unsigned short* __restrict__ keys, unsigned* __restrict__ hist1) {
  int blk = blockIdx.x;              // 40 * 32
  int j = blk >> 5, seg = blk & 31;  // 8192 keys per segment
  const uint4* kp = (const uint4*)(keys + (size_t)j * NPIX + seg * 8192);
  __shared__ unsigned lh[2048];      // 256 bins x 8 copies
  for (int i = threadIdx.x; i < 2048; i += 256) lh[i] = 0u;
  __syncthreads();
  int c = threadIdx.x & 7;
#pragma unroll
  for (int it = 0; it < 4; ++it) {
    uint4 k4 = kp[threadIdx.x + it * 256];
    unsigned w[4] = {k4.x, k4.y, k4.z, k4.w};
#pragma unroll
    for (int e = 0; e < 4; ++e) {
      atomicAdd(&lh[((w[e] & 0xFFFFu) >> 8) * 8 + c], 1u);
      atomicAdd(&lh[(w[e] >> 24) * 8 + c], 1u);
    }
  }
  __syncthreads();
  unsigned s = 0;
#pragma unroll
  for (int k = 0; k < 8; ++k) s += lh[threadIdx.x * 8 + k];
  if (s) atomicAdd(&hist1[j * 256 + threadIdx.x], s);
}

// Coarse: find high-byte bin b1 (descending); A1 = count strictly above.
__global__ void scan1_kernel(const unsigned* __restrict__ hist1,
                             int* __restrict__ st) {
  int j = blockIdx.x;
  const unsigned* h = hist1 + j * 256;
  __shared__ unsigned cs[256];
  int tid = threadIdx.x;
  cs[tid] = h[tid];
  __syncthreads();
  if (tid == 0) {
    unsigned cum = 0; int b1 = 255; unsigned A1 = 0;
    for (int c = 255; c >= 0; --c) {
      if (cum + cs[c] >= (unsigned)KSEL) { b1 = c; A1 = cum; break; }
      cum += cs[c];
    }
    st[j * 4 + 0] = b1;
    st[j * 4 + 1] = (int)A1;
  }
}

// Refine: histogram low byte for u16 keys whose high byte == b1.
__global__ __launch_bounds__(256) void hist2_kernel(
    const unsigned short* __restrict__ keys, const int* __restrict__ st,
    unsigned* __restrict__ hist2) {
  int blk = blockIdx.x;              // 40 * 32
  int j = blk >> 5, seg = blk & 31;
  unsigned b1 = (unsigned)st[j * 4 + 0];
  const uint4* kp = (const uint4*)(keys + (size_t)j * NPIX + seg * 8192);
  __shared__ unsigned lh[256];
  lh[threadIdx.x] = 0u;
  __syncthreads();
#pragma unroll
  for (int it = 0; it < 4; ++it) {
    uint4 k4 = kp[threadIdx.x + it * 256];
    unsigned w[4] = {k4.x, k4.y, k4.z, k4.w};
#pragma unroll
    for (int e = 0; e < 4; ++e) {
      unsigned lo = w[e] & 0xFFFFu, hi = w[e] >> 16;
      if ((lo >> 8) == b1) atomicAdd(&lh[lo & 255u], 1u);
      if ((hi >> 8) == b1) atomicAdd(&lh[hi & 255u], 1u);
    }
  }
  __syncthreads();
  if (lh[threadIdx.x]) atomicAdd(&hist2[j * 256 + threadIdx.x], lh[threadIdx.x]);
}

// pstar = (b1<<8)|b2 (full u16 prefix); A2 = exact count of keys > pstar.
__global__ void scan2_kernel(const unsigned* __restrict__ hist2,
                             int* __restrict__ st) {
  int j = blockIdx.x;
  const unsigned* h = hist2 + j * 256;
  __shared__ unsigned cs[256];
  int tid = threadIdx.x;
  cs[tid] = h[tid];
  __syncthreads();
  if (tid == 0) {
    unsigned b1 = (unsigned)st[j * 4 + 0];
    unsigned A1 = (unsigned)st[j * 4 + 1];
    unsigned cum = A1; int b2 = 255; unsigned A2 = A1;
    for (int c = 255; c >= 0; --c) {
      if (cum + cs[c] >= (unsigned)KSEL) { b2 = c; A2 = cum; break; }
      cum += cs[c];
    }
    st[j * 4 + 2] = (int)((b1 << 8) | (unsigned)b2);
    st[j * 4 + 3] = (int)A2;
  }
}

// Decided bits: key > pstar+KAPPA -> 1, key < pstar-KAPPA -> 0.
// In-band keys -> gather (idx, key) for exact f64 resolution.
__global__ __launch_bounds__(256) void mask_gather_kernel(
    const unsigned short* __restrict__ keys, const int* __restrict__ st,
    float* __restrict__ out, unsigned* __restrict__ ccount,
    int* __restrict__ cidx, unsigned short* __restrict__ ckey) {
  int blk = blockIdx.x;              // 40 * 32
  int j = blk >> 5, seg = blk & 31;
  int b = j / 5, l = j % 5 + 1;
  int rowg = b * 6 + l;
  int pstar = st[j * 4 + 2];
  const uint4* kp = (const uint4*)(keys + (size_t)j * NPIX + seg * 8192);
  float4* o4 = (float4*)(out + (size_t)rowg * NPIX + seg * 8192);
#pragma unroll
  for (int it = 0; it < 4; ++it) {
    int q = threadIdx.x + it * 256;
    uint4 k4 = kp[q];                // 8 u16 keys
    unsigned w[4] = {k4.x, k4.y, k4.z, k4.w};
    float4 mv[2];
    float* mf = (float*)mv;
#pragma unroll
    for (int e = 0; e < 4; ++e) {
      int lo = (int)(w[e] & 0xFFFFu);
      int hi = (int)(w[e] >> 16);
      mf[e * 2]     = lo > pstar + KAPPA ? 1.f : 0.f;
      mf[e * 2 + 1] = hi > pstar + KAPPA ? 1.f : 0.f;
      if (lo >= pstar - KAPPA && lo <= pstar + KAPPA) {
        unsigned s = atomicAdd(&ccount[j], 1u);
        if (s < CAND_CAP) { cidx[j * CAND_CAP + s] = seg * 8192 + q * 8 + e * 2;
                            ckey[j * CAND_CAP + s] = (unsigned short)lo; }
      }
      if (hi >= pstar - KAPPA && hi <= pstar + KAPPA) {
        unsigned s = atomicAdd(&ccount[j], 1u);
        if (s < CAND_CAP) { cidx[j * CAND_CAP + s] = seg * 8192 + q * 8 + e * 2 + 1;
                            ckey[j * CAND_CAP + s] = (unsigned short)hi; }
      }
    }
    o4[q * 2] = mv[0];
    o4[q * 2 + 1] = mv[1];
  }
}

// Wide exact f64 recompute: one thread per candidate, strided across 16
// blocks per row so work spreads over the whole grid.
__global__ __launch_bounds__(256) void cand_eval_kernel(
    const float* __restrict__ conf, const float* __restrict__ warp,
    const float* __restrict__ gk, const unsigned* __restrict__ ccount,
    const int* __restrict__ cidx, double* __restrict__ cval) {
  int blk = blockIdx.x;              // 40 * 16
  int j = blk >> 4, s = blk & 15;
  int C = (int)min(ccount[j], (unsigned)CAND_CAP);
  int i = (int)threadIdx.x * 16 + s;
  if (i >= C) return;
  int b = j / 5, l = j % 5 + 1;
  int rowg = b * 6 + l;
  const float* confr = conf + (size_t)rowg * 4u * NPIX;
  const float* warpr = warp + (size_t)b * NPIX;
  int idx = cidx[j * CAND_CAP + i];
  int y = idx >> 9, x = idx & 511;
  double acc = 0.0;
#pragma unroll
  for (int dy = 0; dy < 5; ++dy)
#pragma unroll
    for (int dx = 0; dx < 5; ++dx)
      acc = fma((double)gk[dy * 5 + dx], m_val(confr, warpr, y + dy - 2, x + dx - 2), acc);
  cval[j * CAND_CAP + i] = acc;
}

// Exact rank with (value desc, index asc) tie-break over LDS-resident band.
// R = K - A2 + #(cand key > pstar).
__global__ __launch_bounds__(256) void rank_write_kernel(
    const int* __restrict__ st, const unsigned* __restrict__ ccount,
    const int* __restrict__ cidx, const unsigned short* __restrict__ ckey,
    const double* __restrict__ cval, float* __restrict__ out) {
  int j = blockIdx.x;
  int b = j / 5, l = j % 5 + 1;
  int rowg = b * 6 + l;
  __shared__ double vs[CAND_CAP];    // 32 KB
  __shared__ int ids[CAND_CAP];      // 16 KB
  int tid = threadIdx.x;
  int pstar = st[j * 4 + 2];
  int A2 = st[j * 4 + 3];
  int C = (int)min(ccount[j], (unsigned)CAND_CAP);
  for (int i = tid; i < C; i += 256) {
    vs[i] = cval[j * CAND_CAP + i];
    ids[i] = cidx[j * CAND_CAP + i];
  }
  __syncthreads();
  int cntAbove = 0;
  for (int q = 0; q < C; ++q)
    cntAbove += (int)ckey[j * CAND_CAP + q] > pstar ? 1 : 0;
  int R = KSEL - A2 + cntAbove;
  for (int i = tid; i < C; i += 256) {
    double vi = vs[i];
    int ii = ids[i];
    int rank = 0;
    for (int q = 0; q < C; ++q) {
      double vq = vs[q];
      rank += (vq > vi) || (vq == vi && ids[q] < ii) ? 1 : 0;
    }
    if (rank < R) out[(size_t)rowg * NPIX + ii] = 1.0f;
  }
  if (j == 0 && tid == 0) out[12582912] = 0.5f;  // rate == 0.5 exactly
}

extern "C" void kernel_launch(void* const* d_in, const int* in_sizes, int n_in,
                              void* d_out, int out_size, void* d_ws, size_t ws_size,
                              hipStream_t stream) {
  const float* conf = (const float*)d_in[0];
  const float* warp = (const float*)d_in[1];
  const float* gk   = (const float*)d_in[2];
  float* out = (float*)d_out;
  char* ws = (char*)d_ws;

  unsigned short* keys = (unsigned short*)(ws + OFF_KEY);
  unsigned* h1 = (unsigned*)(ws + OFF_H1);
  unsigned* h2 = (unsigned*)(ws + OFF_H2);
  int*      st = (int*)(ws + OFF_ST);
  unsigned* cc = (unsigned*)(ws + OFF_CC);
  int*      ci = (int*)(ws + OFF_CI);
  unsigned short* ck = (unsigned short*)(ws + OFF_CK);
  double*   cv = (double*)(ws + OFF_CV);

  hipMemsetAsync(ws + OFF_H1, 0, (size_t)META_BYTES, stream);

  ego_fill_kernel<<<2048, 256, 0, stream>>>(out);
  compute_kernel<<<NROWSEL * 64, 256, 0, stream>>>(conf, warp, gk, keys);
  hist1_kernel<<<NROWSEL * 32, 256, 0, stream>>>(keys, h1);
  scan1_kernel<<<NROWSEL, 256, 0, stream>>>(h1, st);
  hist2_kernel<<<NROWSEL * 32, 256, 0, stream>>>(keys, st, h2);
  scan2_kernel<<<NROWSEL, 256, 0, stream>>>(h2, st);
  mask_gather_kernel<<<NROWSEL * 32, 256, 0, stream>>>(keys, st, out, cc, ci, ck);
  cand_eval_kernel<<<NROWSEL * 16, 256, 0, stream>>>(conf, warp, gk, cc, ci, cv);
  rank_write_kernel<<<NROWSEL, 256, 0, stream>>>(st, cc, ci, ck, cv, out);
}